// Round 9
// baseline (344.421 us; speedup 1.0000x reference)
//
#include <hip/hip_runtime.h>
#include <cstdint>
#include <cstddef>

// Problem constants: B=2, T=32, S=1024, D=512, H=8, hd=64, inner=512
#define KDIM 512

typedef __attribute__((ext_vector_type(8))) __bf16 bf16x8;
typedef __attribute__((ext_vector_type(8))) unsigned short ushort8;
typedef __attribute__((ext_vector_type(4))) float f32x4;
typedef unsigned short u16;

__device__ __forceinline__ float bf2f(u16 u) {
  union { unsigned u32; float f; } x; x.u32 = ((unsigned)u) << 16; return x.f;
}
__device__ __forceinline__ u16 f2bf(float f) {
  union { float f; unsigned u; } x; x.f = f;
  unsigned u = x.u;
  unsigned r = (u + 0x7fffu + ((u >> 16) & 1u)) >> 16;
  return (u16)r;
}

// ---------------- cast x (fp32 -> bf16), vectorized float4 ----------------
__global__ __launch_bounds__(256) void cast_x_kernel(const float* __restrict__ in,
                                                     u16* __restrict__ out, int n4) {
  int i = blockIdx.x * 256 + threadIdx.x;
  if (i >= n4) return;
  float4 v = ((const float4*)in)[i];
  ushort4 o;
  o.x = f2bf(v.x); o.y = f2bf(v.y); o.z = f2bf(v.z); o.w = f2bf(v.w);
  ((ushort4*)out)[i] = o;
}

// ---------------- transpose + cast W: in[R][C] fp32 -> out[C][R] bf16 ------
__global__ __launch_bounds__(256) void transpose_cast_kernel(const float* __restrict__ in,
                                                             u16* __restrict__ out,
                                                             int R, int C) {
  int o = blockIdx.x * 256 + threadIdx.x;
  if (o >= R * C) return;
  int r = o % R;
  int c = o / R;
  out[o] = f2bf(in[(size_t)r * C + c]);
}

__device__ __forceinline__ void gload_lds16(const void* g, void* l) {
  __builtin_amdgcn_global_load_lds((__attribute__((address_space(1))) unsigned int*)g,
                                   (__attribute__((address_space(3))) unsigned int*)l,
                                   16, 0, 0);
}

// ---------------- 256x256 ring-4 GEMM1 (measured best: R5, 138us) -----------
// C[M][N] bf16 = A[M][512] * Bt[N][512]^T.  512 threads = 8 waves (2M x 4N);
// per-wave 128x64, acc[8][4].  BK=32 -> 16 K-tiles, LDS ring of 4 slots.
__global__ __launch_bounds__(512, 2) void gemm256_kernel(const u16* __restrict__ A,
                                                         const u16* __restrict__ Bt,
                                                         u16* __restrict__ C,
                                                         int N, int NXT) {
  __shared__ __attribute__((aligned(16))) u16 As[4][8192];
  __shared__ __attribute__((aligned(16))) u16 Bs[4][8192];
  const int tid = threadIdx.x;
  const int wid = tid >> 6, l = tid & 63;
  const int wm = wid >> 2, wn = wid & 3;
  const int g = l >> 4, i = l & 15;

  const int nwg = gridDim.x;
  const int cpx = nwg >> 3;
  const int bid = blockIdx.x;
  const int swz = (bid & 7) * cpx + (bid >> 3);
  const int mt = swz / NXT, nt = swz % NXT;
  const size_t m0 = (size_t)mt * 256, n0 = (size_t)nt * 256;

  const int srow = tid >> 2;
  const int sbp = tid & 3;
  const int sbs = sbp ^ ((srow >> 1) & 3);

  f32x4 acc[8][4] = {};

  auto STAGE = [&](int t, int slot) {
    const int k0 = t << 5;
    gload_lds16(A + (m0 + srow) * KDIM + k0 + sbs * 8, &As[slot][tid * 8]);
    gload_lds16(A + (m0 + 128 + srow) * KDIM + k0 + sbs * 8, &As[slot][(tid + 512) * 8]);
    gload_lds16(Bt + (n0 + srow) * KDIM + k0 + sbs * 8, &Bs[slot][tid * 8]);
    gload_lds16(Bt + (n0 + 128 + srow) * KDIM + k0 + sbs * 8, &Bs[slot][(tid + 512) * 8]);
  };

  auto COMPUTE = [&](int slot) {
    bf16x8 af[8], bv[4];
#pragma unroll
    for (int m = 0; m < 8; ++m) {
      int row = wm * 128 + m * 16 + i;
      af[m] = *(const bf16x8*)&As[slot][row * 32 + ((g ^ ((row >> 1) & 3)) << 3)];
    }
#pragma unroll
    for (int n = 0; n < 4; ++n) {
      int row = wn * 64 + n * 16 + i;
      bv[n] = *(const bf16x8*)&Bs[slot][row * 32 + ((g ^ ((row >> 1) & 3)) << 3)];
    }
    __builtin_amdgcn_s_setprio(1);
#pragma unroll
    for (int m = 0; m < 8; ++m)
#pragma unroll
      for (int n = 0; n < 4; ++n)
        acc[m][n] = __builtin_amdgcn_mfma_f32_16x16x32_bf16(af[m], bv[n], acc[m][n], 0, 0, 0);
    __builtin_amdgcn_s_setprio(0);
  };

  STAGE(0, 0);
  STAGE(1, 1);
  STAGE(2, 2);
  for (int t = 0; t < 14; ++t) {
    asm volatile("s_waitcnt vmcnt(8)" ::: "memory");
    __builtin_amdgcn_s_barrier();
    __builtin_amdgcn_sched_barrier(0);
    if (t < 13) STAGE(t + 3, (t + 3) & 3);
    COMPUTE(t & 3);
    __builtin_amdgcn_sched_barrier(0);
  }
  asm volatile("s_waitcnt vmcnt(4)" ::: "memory");
  __builtin_amdgcn_s_barrier();
  __builtin_amdgcn_sched_barrier(0);
  COMPUTE(2);
  __builtin_amdgcn_sched_barrier(0);
  asm volatile("s_waitcnt vmcnt(0)" ::: "memory");
  __builtin_amdgcn_s_barrier();
  __builtin_amdgcn_sched_barrier(0);
  COMPUTE(3);

#pragma unroll
  for (int m = 0; m < 8; ++m) {
    size_t rowb = m0 + wm * 128 + m * 16 + g * 4;
#pragma unroll
    for (int n = 0; n < 4; ++n) {
      size_t colg = n0 + wn * 64 + n * 16 + i;
#pragma unroll
      for (int r = 0; r < 4; ++r)
        C[(rowb + r) * (size_t)N + colg] = f2bf(acc[m][n][r]);
    }
  }
}

// ---------------- fused temporal attention + out-projection -----------------
// Block = (b, s). 512 threads = 8 waves; phase 1: wave = head (proven attn
// body).  O (32x512 bf16) never leaves LDS: O-chunk of wave wv overlays the
// dead Vt[wv] (write-side XOR swizzle; plain ds_write so no gload constraint).
// Ps overlays dead Ks (per-wave private; QK^T reads completed before the
// MFMAs consumed them, writes come later in program order -> no hazard).
// Phase 2 (after __syncthreads): out[32][512] fp32 = O @ Wout.  Wave wv owns
// cols [wv*64,+64): acc2[2][4]; A-frags b128 from LDS-O (swizzle-matched),
// B-frags streamed from L2-resident wout_t.  LDS 64KB -> 2 blocks/CU.
__global__ __launch_bounds__(512, 4) void attn_out_kernel(const u16* __restrict__ qkv,
                                                          const u16* __restrict__ wout_t,
                                                          float* __restrict__ outp) {
  const int bs = blockIdx.x;
  const int b = bs >> 10, s = bs & 1023;
  __shared__ __attribute__((aligned(16))) u16 Ks[8][2048];  // first 1024/wave reused as Ps
  __shared__ __attribute__((aligned(16))) u16 Vt[8][2048];  // later: O chunk [32q][64d] swz

  const int tid = threadIdx.x;
  const int wv = tid >> 6;
  const int h = wv;
  const int l = tid & 63;
  const int g = l >> 4, i = l & 15;

  const size_t tstride = (size_t)1024 * 1536;
  const size_t base = ((size_t)(b * 32) * 1024 + s) * 1536;

  // ---- stage K via global_load_lds (pre-swizzled source) ------------------
  {
    const int krow = l >> 3;
    const int dbs = (l & 7) ^ krow;
#pragma unroll
    for (int j = 0; j < 4; ++j) {
      int k = j * 8 + krow;
      gload_lds16(qkv + base + (size_t)k * tstride + 512 + h * 64 + dbs * 8, &Ks[wv][j * 512]);
    }
  }

  // ---- V reg-stage + transpose into Vt (XOR swizzle) ----------------------
  const int vk = l & 31;
  ushort8 vv[4];
#pragma unroll
  for (int j = 0; j < 4; ++j) {
    int c = (l >> 5) + 2 * j;
    vv[j] = *(const ushort8*)(qkv + base + (size_t)vk * tstride + 1024 + h * 64 + c * 8);
  }

  bf16x8 bq[2][2];
#pragma unroll
  for (int n = 0; n < 2; ++n)
#pragma unroll
    for (int ks = 0; ks < 2; ++ks)
      bq[n][ks] = *(const bf16x8*)(qkv + base + (size_t)(n * 16 + i) * tstride + h * 64 + ks * 32 + g * 8);

#pragma unroll
  for (int j = 0; j < 4; ++j) {
    int c = (l >> 5) + 2 * j;
#pragma unroll
    for (int u = 0; u < 8; ++u) {
      int d = c * 8 + u;
      int pos = (vk >> 3) ^ (d & 3);
      Vt[wv][d * 32 + pos * 8 + (vk & 7)] = vv[j][u];
    }
  }

  asm volatile("s_waitcnt vmcnt(0)" ::: "memory");

  // ---- QK^T (swapped) -----------------------------------------------------
  f32x4 sc[2][2] = {};
#pragma unroll
  for (int m = 0; m < 2; ++m)
#pragma unroll
    for (int ks = 0; ks < 2; ++ks) {
      int k = m * 16 + i;
      int pos = (ks * 4 + g) ^ (k & 7);
      bf16x8 ak = *(const bf16x8*)&Ks[wv][k * 64 + pos * 8];
      sc[m][0] = __builtin_amdgcn_mfma_f32_16x16x32_bf16(ak, bq[0][ks], sc[m][0], 0, 0, 0);
      sc[m][1] = __builtin_amdgcn_mfma_f32_16x16x32_bf16(ak, bq[1][ks], sc[m][1], 0, 0, 0);
    }

  // ---- softmax ------------------------------------------------------------
  float p[2][2][4];
#pragma unroll
  for (int n = 0; n < 2; ++n) {
    int q = n * 16 + i;
    float m0 = -1e30f;
#pragma unroll
    for (int m = 0; m < 2; ++m)
#pragma unroll
      for (int r = 0; r < 4; ++r) {
        int k = m * 16 + g * 4 + r;
        float v = (k <= q) ? sc[m][n][r] * 0.125f : -1e30f;
        p[m][n][r] = v;
        m0 = fmaxf(m0, v);
      }
    m0 = fmaxf(m0, __shfl_xor(m0, 16));
    m0 = fmaxf(m0, __shfl_xor(m0, 32));
    float s0 = 0.f;
#pragma unroll
    for (int m = 0; m < 2; ++m)
#pragma unroll
      for (int r = 0; r < 4; ++r) {
        float e = __expf(p[m][n][r] - m0);
        p[m][n][r] = e;
        s0 += e;
      }
    s0 += __shfl_xor(s0, 16);
    s0 += __shfl_xor(s0, 32);
    float inv = 1.f / s0;
#pragma unroll
    for (int m = 0; m < 2; ++m)
#pragma unroll
      for (int r = 0; r < 4; ++r) p[m][n][r] *= inv;
  }

  // ---- pack P^T into Ps (overlay on Ks[wv], per-wave private) -------------
  u16* Psw = &Ks[wv][0];
#pragma unroll
  for (int m = 0; m < 2; ++m)
#pragma unroll
    for (int n = 0; n < 2; ++n) {
      int q = n * 16 + i;
      int kb = m * 2 + (g >> 1);
      int pos = kb ^ (q & 3);
      uint2 wo;
      wo.x = (unsigned)f2bf(p[m][n][0]) | ((unsigned)f2bf(p[m][n][1]) << 16);
      wo.y = (unsigned)f2bf(p[m][n][2]) | ((unsigned)f2bf(p[m][n][3]) << 16);
      *(uint2*)&Psw[q * 32 + pos * 8 + (g & 1) * 4] = wo;
    }

  asm volatile("s_waitcnt lgkmcnt(0)" ::: "memory");

  // ---- PV -----------------------------------------------------------------
  bf16x8 bvf[4];
#pragma unroll
  for (int np = 0; np < 4; ++np) {
    int d = np * 16 + i;
    int pos = g ^ (d & 3);
    bvf[np] = *(const bf16x8*)&Vt[wv][d * 32 + pos * 8];
  }
  f32x4 o[2][4] = {};
#pragma unroll
  for (int mp = 0; mp < 2; ++mp) {
    int q = mp * 16 + i;
    int pos = g ^ (q & 3);
    bf16x8 ap = *(const bf16x8*)&Psw[q * 32 + pos * 8];
#pragma unroll
    for (int np = 0; np < 4; ++np)
      o[mp][np] = __builtin_amdgcn_mfma_f32_16x16x32_bf16(ap, bvf[np], o[mp][np], 0, 0, 0);
  }

  // ---- write O chunk into Vt[wv] (dead after PV; swizzled for b128 reads) -
  // O[q][d_in_head]; u16 idx = q*64 + ((d>>3) ^ (q&7))*8 + (d&7)
#pragma unroll
  for (int mp = 0; mp < 2; ++mp)
#pragma unroll
    for (int r = 0; r < 4; ++r) {
      int q = mp * 16 + g * 4 + r;
#pragma unroll
      for (int np = 0; np < 4; ++np) {
        int d = np * 16 + i;
        Vt[wv][q * 64 + ((((d >> 3)) ^ (q & 7)) << 3) + (d & 7)] = f2bf(o[mp][np][r]);
      }
    }

  __syncthreads();

  // ---- phase 2: out[32][512] = O @ Wout; wave wv -> cols [wv*64,+64) ------
  f32x4 acc2[2][4] = {};
#pragma unroll 4
  for (int ks = 0; ks < 16; ++ks) {
    bf16x8 af2[2];
#pragma unroll
    for (int mf = 0; mf < 2; ++mf) {
      int q = mf * 16 + i;
      int dblk = (ks & 1) * 4 + g;            // 16B block within 64-d chunk
      af2[mf] = *(const bf16x8*)&Vt[ks >> 1][q * 64 + ((dblk ^ (q & 7)) << 3)];
    }
    bf16x8 bw[4];
#pragma unroll
    for (int n = 0; n < 4; ++n)
      bw[n] = *(const bf16x8*)(wout_t + (size_t)(wv * 64 + n * 16 + i) * 512 + ks * 32 + g * 8);
#pragma unroll
    for (int mf = 0; mf < 2; ++mf)
#pragma unroll
      for (int n = 0; n < 4; ++n)
        acc2[mf][n] = __builtin_amdgcn_mfma_f32_16x16x32_bf16(af2[mf], bw[n], acc2[mf][n], 0, 0, 0);
  }

  // ---- store fp32 out -----------------------------------------------------
#pragma unroll
  for (int mf = 0; mf < 2; ++mf)
#pragma unroll
    for (int r = 0; r < 4; ++r) {
      int q = mf * 16 + g * 4 + r;
      float* dst = outp + ((size_t)((b * 32 + q) * 1024 + s)) * 512 + wv * 64;
#pragma unroll
      for (int n = 0; n < 4; ++n)
        dst[n * 16 + i] = acc2[mf][n][r];
    }
}

// ---------------------------------------------------------------------------
extern "C" void kernel_launch(void* const* d_in, const int* in_sizes, int n_in,
                              void* d_out, int out_size, void* d_ws, size_t ws_size,
                              hipStream_t stream) {
  const float* x = (const float*)d_in[0];     // [2,32,1024,512] fp32
  const float* Wqkv = (const float*)d_in[1];  // [512,1536] fp32
  const float* Wout = (const float*)d_in[2];  // [512,512] fp32
  float* outp = (float*)d_out;                // [2,32,1024,512] fp32

  char* ws = (char*)d_ws;
  u16* x_bf = (u16*)(ws);                                // 64 MiB
  u16* qkv_bf = (u16*)(ws + (size_t)67108864);           // 192 MiB
  u16* wqkv_t = (u16*)(ws + (size_t)268435456);          // 1.5 MiB
  u16* wout_t = (u16*)(ws + (size_t)270008320);          // 0.5 MiB

  // 1) casts
  cast_x_kernel<<<32768, 256, 0, stream>>>(x, x_bf, 8388608);
  transpose_cast_kernel<<<3072, 256, 0, stream>>>(Wqkv, wqkv_t, 512, 1536);
  transpose_cast_kernel<<<1024, 256, 0, stream>>>(Wout, wout_t, 512, 512);

  // 2) QKV GEMM: [65536,512] x [512,1536] -> [65536,1536] bf16 (R5 ring-4)
  gemm256_kernel<<<1536, 512, 0, stream>>>(x_bf, wqkv_t, qkv_bf, 1536, 6);

  // 3) fused temporal attention + out-projection -> fp32 out
  attn_out_kernel<<<2048, 512, 0, stream>>>(qkv_bf, wout_t, outp);
}

// Round 11
// 303.584 us; speedup vs baseline: 1.1345x; 1.1345x over previous
//
#include <hip/hip_runtime.h>
#include <cstdint>
#include <cstddef>

// Problem constants: B=2, T=32, S=1024, D=512, H=8, hd=64, inner=512
#define KDIM 512

typedef __attribute__((ext_vector_type(8))) __bf16 bf16x8;
typedef __attribute__((ext_vector_type(8))) unsigned short ushort8;
typedef __attribute__((ext_vector_type(4))) float f32x4;
typedef unsigned short u16;

__device__ __forceinline__ float bf2f(u16 u) {
  union { unsigned u32; float f; } x; x.u32 = ((unsigned)u) << 16; return x.f;
}
__device__ __forceinline__ u16 f2bf(float f) {
  union { float f; unsigned u; } x; x.f = f;
  unsigned u = x.u;
  unsigned r = (u + 0x7fffu + ((u >> 16) & 1u)) >> 16;
  return (u16)r;
}

// ---------------- cast x (fp32 -> bf16), vectorized float4 ----------------
__global__ __launch_bounds__(256) void cast_x_kernel(const float* __restrict__ in,
                                                     u16* __restrict__ out, int n4) {
  int i = blockIdx.x * 256 + threadIdx.x;
  if (i >= n4) return;
  float4 v = ((const float4*)in)[i];
  ushort4 o;
  o.x = f2bf(v.x); o.y = f2bf(v.y); o.z = f2bf(v.z); o.w = f2bf(v.w);
  ((ushort4*)out)[i] = o;
}

// ---------------- transpose + cast W: in[R][C] fp32 -> out[C][R] bf16 ------
__global__ __launch_bounds__(256) void transpose_cast_kernel(const float* __restrict__ in,
                                                             u16* __restrict__ out,
                                                             int R, int C) {
  int o = blockIdx.x * 256 + threadIdx.x;
  if (o >= R * C) return;
  int r = o % R;
  int c = o / R;
  out[o] = f2bf(in[(size_t)r * C + c]);
}

__device__ __forceinline__ void gload_lds16(const void* g, void* l) {
  __builtin_amdgcn_global_load_lds((__attribute__((address_space(1))) unsigned int*)g,
                                   (__attribute__((address_space(3))) unsigned int*)l,
                                   16, 0, 0);
}

// ---------------- 256x256 ring-4 GEMM1 (verbatim R5/R6-passing, ~138us) -----
// C[M][N] bf16 = A[M][512] * Bt[N][512]^T.  512 threads = 8 waves (2M x 4N);
// per-wave 128x64, acc[8][4].  BK=32 -> 16 K-tiles, LDS ring of 4 slots.
// One barrier per tile; vmcnt(8) counted wait (2 tiles in flight); STAGE 3
// tiles ahead into slot (t+3)&3 = (t-1)&3 whose reads finished pre-barrier.
__global__ __launch_bounds__(512, 2) void gemm256_kernel(const u16* __restrict__ A,
                                                         const u16* __restrict__ Bt,
                                                         u16* __restrict__ C,
                                                         int N, int NXT) {
  __shared__ __attribute__((aligned(16))) u16 As[4][8192];
  __shared__ __attribute__((aligned(16))) u16 Bs[4][8192];
  const int tid = threadIdx.x;
  const int wid = tid >> 6, l = tid & 63;
  const int wm = wid >> 2, wn = wid & 3;
  const int g = l >> 4, i = l & 15;

  const int nwg = gridDim.x;
  const int cpx = nwg >> 3;
  const int bid = blockIdx.x;
  const int swz = (bid & 7) * cpx + (bid >> 3);
  const int mt = swz / NXT, nt = swz % NXT;
  const size_t m0 = (size_t)mt * 256, n0 = (size_t)nt * 256;

  const int srow = tid >> 2;
  const int sbp = tid & 3;
  const int sbs = sbp ^ ((srow >> 1) & 3);

  f32x4 acc[8][4] = {};

  auto STAGE = [&](int t, int slot) {
    const int k0 = t << 5;
    gload_lds16(A + (m0 + srow) * KDIM + k0 + sbs * 8, &As[slot][tid * 8]);
    gload_lds16(A + (m0 + 128 + srow) * KDIM + k0 + sbs * 8, &As[slot][(tid + 512) * 8]);
    gload_lds16(Bt + (n0 + srow) * KDIM + k0 + sbs * 8, &Bs[slot][tid * 8]);
    gload_lds16(Bt + (n0 + 128 + srow) * KDIM + k0 + sbs * 8, &Bs[slot][(tid + 512) * 8]);
  };

  auto COMPUTE = [&](int slot) {
    bf16x8 af[8], bv[4];
#pragma unroll
    for (int m = 0; m < 8; ++m) {
      int row = wm * 128 + m * 16 + i;
      af[m] = *(const bf16x8*)&As[slot][row * 32 + ((g ^ ((row >> 1) & 3)) << 3)];
    }
#pragma unroll
    for (int n = 0; n < 4; ++n) {
      int row = wn * 64 + n * 16 + i;
      bv[n] = *(const bf16x8*)&Bs[slot][row * 32 + ((g ^ ((row >> 1) & 3)) << 3)];
    }
    __builtin_amdgcn_s_setprio(1);
#pragma unroll
    for (int m = 0; m < 8; ++m)
#pragma unroll
      for (int n = 0; n < 4; ++n)
        acc[m][n] = __builtin_amdgcn_mfma_f32_16x16x32_bf16(af[m], bv[n], acc[m][n], 0, 0, 0);
    __builtin_amdgcn_s_setprio(0);
  };

  STAGE(0, 0);
  STAGE(1, 1);
  STAGE(2, 2);
  for (int t = 0; t < 14; ++t) {
    asm volatile("s_waitcnt vmcnt(8)" ::: "memory");
    __builtin_amdgcn_s_barrier();
    __builtin_amdgcn_sched_barrier(0);
    if (t < 13) STAGE(t + 3, (t + 3) & 3);
    COMPUTE(t & 3);
    __builtin_amdgcn_sched_barrier(0);
  }
  asm volatile("s_waitcnt vmcnt(4)" ::: "memory");
  __builtin_amdgcn_s_barrier();
  __builtin_amdgcn_sched_barrier(0);
  COMPUTE(2);
  __builtin_amdgcn_sched_barrier(0);
  asm volatile("s_waitcnt vmcnt(0)" ::: "memory");
  __builtin_amdgcn_s_barrier();
  __builtin_amdgcn_sched_barrier(0);
  COMPUTE(3);

#pragma unroll
  for (int m = 0; m < 8; ++m) {
    size_t rowb = m0 + wm * 128 + m * 16 + g * 4;
#pragma unroll
    for (int n = 0; n < 4; ++n) {
      size_t colg = n0 + wn * 64 + n * 16 + i;
#pragma unroll
      for (int r = 0; r < 4; ++r)
        C[(rowb + r) * (size_t)N + colg] = f2bf(acc[m][n][r]);
    }
  }
}

// ---------------- GEMM2: 128x128, BK=32, 4 blocks/CU (verbatim R8-passing) --
__global__ __launch_bounds__(256, 4) void gemm128_kernel(const u16* __restrict__ A,
                                                         const u16* __restrict__ Bt,
                                                         float* __restrict__ C,
                                                         int N, int NXT) {
  __shared__ __attribute__((aligned(16))) u16 As[2][4096];  // 128r x 32k
  __shared__ __attribute__((aligned(16))) u16 Bs[2][4096];
  const int tid = threadIdx.x;
  const int wid = tid >> 6, l = tid & 63;
  const int wm = wid >> 1, wn = wid & 1;
  const int g = l >> 4, i = l & 15;

  const int nwg = gridDim.x;
  const int cpx = nwg >> 3;
  const int bid = blockIdx.x;
  const int swz = (bid & 7) * cpx + (bid >> 3);
  const int mt = swz / NXT, nt = swz % NXT;
  const size_t m0 = (size_t)mt * 128, n0 = (size_t)nt * 128;

  f32x4 acc[4][4] = {};

  auto STAGE = [&](int t, int slot) {
    const int k0 = t << 5;
#pragma unroll
    for (int c = 0; c < 2; ++c) {
      int ch = tid + c * 256;
      int row = ch >> 2;
      int bbs = (ch & 3) ^ ((row >> 1) & 3);
      gload_lds16(A + (m0 + row) * KDIM + k0 + bbs * 8, &As[slot][ch * 8]);
      gload_lds16(Bt + (n0 + row) * KDIM + k0 + bbs * 8, &Bs[slot][ch * 8]);
    }
  };
  auto COMPUTE = [&](int slot) {
    bf16x8 af[4], bv[4];
#pragma unroll
    for (int m = 0; m < 4; ++m) {
      int row = wm * 64 + m * 16 + i;
      af[m] = *(const bf16x8*)&As[slot][row * 32 + ((g ^ ((row >> 1) & 3)) << 3)];
    }
#pragma unroll
    for (int n = 0; n < 4; ++n) {
      int row = wn * 64 + n * 16 + i;
      bv[n] = *(const bf16x8*)&Bs[slot][row * 32 + ((g ^ ((row >> 1) & 3)) << 3)];
    }
    __builtin_amdgcn_s_setprio(1);
#pragma unroll
    for (int m = 0; m < 4; ++m)
#pragma unroll
      for (int n = 0; n < 4; ++n)
        acc[m][n] = __builtin_amdgcn_mfma_f32_16x16x32_bf16(af[m], bv[n], acc[m][n], 0, 0, 0);
    __builtin_amdgcn_s_setprio(0);
  };

  STAGE(0, 0);
  asm volatile("s_waitcnt vmcnt(0)" ::: "memory");
  __builtin_amdgcn_s_barrier();
  for (int t = 0; t < 16; ++t) {
    const int buf = t & 1;
    if (t < 15) STAGE(t + 1, buf ^ 1);
    COMPUTE(buf);
    if (t < 15) {
      asm volatile("s_waitcnt vmcnt(0)" ::: "memory");
      __builtin_amdgcn_s_barrier();
    }
  }

#pragma unroll
  for (int m = 0; m < 4; ++m) {
    size_t rowb = m0 + wm * 64 + m * 16 + g * 4;
#pragma unroll
    for (int n = 0; n < 4; ++n) {
      size_t colg = n0 + wn * 64 + n * 16 + i;
#pragma unroll
      for (int r = 0; r < 4; ++r)
        C[(rowb + r) * (size_t)N + colg] = acc[m][n][r];
    }
  }
}

// ---------------- MFMA temporal attention (verbatim R4-R8-passing, ~45us) ---
// Block = (b, s, head-group of 4). 256 threads = 4 waves, wave = one head.
__global__ __launch_bounds__(256, 4) void attn_mfma_kernel(const u16* __restrict__ qkv,
                                                           u16* __restrict__ out) {
  const int bs = blockIdx.x >> 1;
  const int hg = blockIdx.x & 1;
  const int b = bs >> 10, s = bs & 1023;
  __shared__ __attribute__((aligned(16))) u16 Ks[4][2048];
  __shared__ __attribute__((aligned(16))) u16 Vt[4][2048];
  __shared__ __attribute__((aligned(16))) u16 Ps[4][1024];

  const int tid = threadIdx.x;
  const int wv = tid >> 6;
  const int h = hg * 4 + wv;
  const int l = tid & 63;
  const int g = l >> 4, i = l & 15;

  const size_t tstride = (size_t)1024 * 1536;
  const size_t base = ((size_t)(b * 32) * 1024 + s) * 1536;

  {
    const int krow = l >> 3;
    const int dbs = (l & 7) ^ krow;
#pragma unroll
    for (int j = 0; j < 4; ++j) {
      int k = j * 8 + krow;
      gload_lds16(qkv + base + (size_t)k * tstride + 512 + h * 64 + dbs * 8, &Ks[wv][j * 512]);
    }
  }

  const int vk = l & 31;
  ushort8 vv[4];
#pragma unroll
  for (int j = 0; j < 4; ++j) {
    int c = (l >> 5) + 2 * j;
    vv[j] = *(const ushort8*)(qkv + base + (size_t)vk * tstride + 1024 + h * 64 + c * 8);
  }

  bf16x8 bq[2][2];
#pragma unroll
  for (int n = 0; n < 2; ++n)
#pragma unroll
    for (int ks = 0; ks < 2; ++ks)
      bq[n][ks] = *(const bf16x8*)(qkv + base + (size_t)(n * 16 + i) * tstride + h * 64 + ks * 32 + g * 8);

#pragma unroll
  for (int j = 0; j < 4; ++j) {
    int c = (l >> 5) + 2 * j;
#pragma unroll
    for (int u = 0; u < 8; ++u) {
      int d = c * 8 + u;
      int pos = (vk >> 3) ^ (d & 3);
      Vt[wv][d * 32 + pos * 8 + (vk & 7)] = vv[j][u];
    }
  }

  asm volatile("s_waitcnt vmcnt(0)" ::: "memory");

  f32x4 sc[2][2] = {};
#pragma unroll
  for (int m = 0; m < 2; ++m)
#pragma unroll
    for (int ks = 0; ks < 2; ++ks) {
      int k = m * 16 + i;
      int pos = (ks * 4 + g) ^ (k & 7);
      bf16x8 ak = *(const bf16x8*)&Ks[wv][k * 64 + pos * 8];
      sc[m][0] = __builtin_amdgcn_mfma_f32_16x16x32_bf16(ak, bq[0][ks], sc[m][0], 0, 0, 0);
      sc[m][1] = __builtin_amdgcn_mfma_f32_16x16x32_bf16(ak, bq[1][ks], sc[m][1], 0, 0, 0);
    }

  float p[2][2][4];
#pragma unroll
  for (int n = 0; n < 2; ++n) {
    int q = n * 16 + i;
    float m0 = -1e30f;
#pragma unroll
    for (int m = 0; m < 2; ++m)
#pragma unroll
      for (int r = 0; r < 4; ++r) {
        int k = m * 16 + g * 4 + r;
        float v = (k <= q) ? sc[m][n][r] * 0.125f : -1e30f;
        p[m][n][r] = v;
        m0 = fmaxf(m0, v);
      }
    m0 = fmaxf(m0, __shfl_xor(m0, 16));
    m0 = fmaxf(m0, __shfl_xor(m0, 32));
    float s0 = 0.f;
#pragma unroll
    for (int m = 0; m < 2; ++m)
#pragma unroll
      for (int r = 0; r < 4; ++r) {
        float e = __expf(p[m][n][r] - m0);
        p[m][n][r] = e;
        s0 += e;
      }
    s0 += __shfl_xor(s0, 16);
    s0 += __shfl_xor(s0, 32);
    float inv = 1.f / s0;
#pragma unroll
    for (int m = 0; m < 2; ++m)
#pragma unroll
      for (int r = 0; r < 4; ++r) p[m][n][r] *= inv;
  }

#pragma unroll
  for (int m = 0; m < 2; ++m)
#pragma unroll
    for (int n = 0; n < 2; ++n) {
      int q = n * 16 + i;
      int kb = m * 2 + (g >> 1);
      int pos = kb ^ (q & 3);
      uint2 wo;
      wo.x = (unsigned)f2bf(p[m][n][0]) | ((unsigned)f2bf(p[m][n][1]) << 16);
      wo.y = (unsigned)f2bf(p[m][n][2]) | ((unsigned)f2bf(p[m][n][3]) << 16);
      *(uint2*)&Ps[wv][q * 32 + pos * 8 + (g & 1) * 4] = wo;
    }

  asm volatile("s_waitcnt lgkmcnt(0)" ::: "memory");

  bf16x8 bv[4];
#pragma unroll
  for (int np = 0; np < 4; ++np) {
    int d = np * 16 + i;
    int pos = g ^ (d & 3);
    bv[np] = *(const bf16x8*)&Vt[wv][d * 32 + pos * 8];
  }
  f32x4 o[2][4] = {};
#pragma unroll
  for (int mp = 0; mp < 2; ++mp) {
    int q = mp * 16 + i;
    int pos = g ^ (q & 3);
    bf16x8 ap = *(const bf16x8*)&Ps[wv][q * 32 + pos * 8];
#pragma unroll
    for (int np = 0; np < 4; ++np)
      o[mp][np] = __builtin_amdgcn_mfma_f32_16x16x32_bf16(ap, bv[np], o[mp][np], 0, 0, 0);
  }

#pragma unroll
  for (int mp = 0; mp < 2; ++mp)
#pragma unroll
    for (int r = 0; r < 4; ++r) {
      int q = mp * 16 + g * 4 + r;
      u16* dst = out + ((size_t)((b * 32 + q) * 1024 + s)) * 512 + h * 64;
#pragma unroll
      for (int np = 0; np < 4; ++np)
        dst[np * 16 + i] = f2bf(o[mp][np][r]);
    }
}

// ---------------------------------------------------------------------------
extern "C" void kernel_launch(void* const* d_in, const int* in_sizes, int n_in,
                              void* d_out, int out_size, void* d_ws, size_t ws_size,
                              hipStream_t stream) {
  const float* x = (const float*)d_in[0];     // [2,32,1024,512] fp32
  const float* Wqkv = (const float*)d_in[1];  // [512,1536] fp32
  const float* Wout = (const float*)d_in[2];  // [512,512] fp32
  float* outp = (float*)d_out;                // [2,32,1024,512] fp32

  char* ws = (char*)d_ws;
  u16* x_bf = (u16*)(ws);                                // 64 MiB
  u16* qkv_bf = (u16*)(ws + (size_t)67108864);           // 192 MiB
  u16* wqkv_t = (u16*)(ws + (size_t)268435456);          // 1.5 MiB
  u16* wout_t = (u16*)(ws + (size_t)270008320);          // 0.5 MiB
  u16* attn_o = x_bf;  // alias: x_bf16 dead after GEMM1

  // 1) casts
  cast_x_kernel<<<32768, 256, 0, stream>>>(x, x_bf, 8388608);
  transpose_cast_kernel<<<3072, 256, 0, stream>>>(Wqkv, wqkv_t, 512, 1536);
  transpose_cast_kernel<<<1024, 256, 0, stream>>>(Wout, wout_t, 512, 512);

  // 2) QKV GEMM: [65536,512] x [512,1536] -> [65536,1536] bf16 (R5 ring-4)
  gemm256_kernel<<<1536, 512, 0, stream>>>(x_bf, wqkv_t, qkv_bf, 1536, 6);

  // 3) temporal attention: 2048 (b,s) x 2 head-groups
  attn_mfma_kernel<<<4096, 256, 0, stream>>>(qkv_bf, attn_o);

  // 4) out projection: [65536,512] x [512,512] -> [65536,512] fp32 (R8 128^2)
  gemm128_kernel<<<2048, 256, 0, stream>>>(attn_o, wout_t, outp, 512, 4);
}